// Round 1
// baseline (3495.158 us; speedup 1.0000x reference)
//
#include <hip/hip_runtime.h>
#include <cstdint>
#include <cstddef>

// Problem constants (B=32, D=256, H=W=32, S=2048)
#define D_DIM   256
#define S_SLOTS 2048
#define HW      1024
#define N_TOTAL 32768
#define OUT_RETR_ELEMS 8388608   // 32*256*32*32
#define OUT_ENT_IDX    8388608
#define OUT_WIMG_IDX   8388609

// ---------------- kernel 1: 1/max(||memory_s||, 1e-12) ----------------
__global__ void k_invnorm(const float* __restrict__ mem, float* __restrict__ invn) {
    const int s = blockIdx.x;
    const int l = threadIdx.x; // 0..63, one wave
    const float4 v = reinterpret_cast<const float4*>(mem + (size_t)s * D_DIM)[l];
    float ss = v.x * v.x + v.y * v.y + v.z * v.z + v.w * v.w;
#pragma unroll
    for (int off = 32; off > 0; off >>= 1) ss += __shfl_down(ss, off);
    if (l == 0) invn[s] = 1.0f / fmaxf(sqrtf(ss), 1e-12f);
}

// ---------------- kernel 2: fused addressing + retrieval ----------------
// grid 512 (each block = 64 consecutive pixels of one image), 256 threads.
// LDS: qT[256][64] (d-major, prescaled by 20/||q||), mt[256][64] (d-major raw
// memory tile), ew[64][64] (w=e/Z tile), + small scratch. ~149 KB dynamic.
__global__ __launch_bounds__(256, 1) void k_main(
    const float* __restrict__ feat, const float* __restrict__ mem,
    const float* __restrict__ invn_g, float* __restrict__ out)
{
    extern __shared__ float smem[];
    float* qT     = smem;             // 16384 floats
    float* mt     = qT + 256 * 64;    // 16384
    float* ew     = mt + 256 * 64;    // 4096
    float* invl   = ew + 64 * 64;     // 64
    float* qsc    = invl + 64;        // 64
    float* red    = qsc + 64;         // 256
    float* entred = red + 256;        // 16

    const int tid = threadIdx.x;
    const int blk = blockIdx.x;
    const int b   = blk >> 4;          // 16 blocks per image
    const int p0  = (blk & 15) << 6;   // pixel base within image
    const float* fbase = feat + (size_t)b * (D_DIM * HW);

    // ---- stage query tile transposed: qT[d][ql] = feat[b][d][p0+ql] ----
    {
        const int dl = tid >> 6, ql = tid & 63;
#pragma unroll 8
        for (int it = 0; it < 64; ++it) {
            const int d = it * 4 + dl;
            qT[d * 64 + ql] = fbase[d * HW + p0 + ql];
        }
    }
    __syncthreads();
    // ---- query norms ----
    {
        const int ql = tid & 63, part = tid >> 6;
        float ss = 0.f;
#pragma unroll 8
        for (int dd = 0; dd < 64; ++dd) {
            const float v = qT[(part * 64 + dd) * 64 + ql];
            ss += v * v;
        }
        red[part * 64 + ql] = ss;
    }
    __syncthreads();
    if (tid < 64) {
        const float ss = red[tid] + red[64 + tid] + red[128 + tid] + red[192 + tid];
        // fold 1/temperature = 20 into the query scale
        qsc[tid] = 20.0f / fmaxf(sqrtf(ss), 1e-12f);
    }
    __syncthreads();
    {
        const int dl = tid >> 6, ql = tid & 63;
        const float sc = qsc[ql];
#pragma unroll 8
        for (int it = 0; it < 64; ++it) {
            const int d = it * 4 + dl;
            qT[d * 64 + ql] *= sc;
        }
    }

    const int sg = tid & 15, qg = tid >> 4;
    const int q0 = qg * 4, s0l = sg * 4;

    float Zp[4] = {0.f, 0.f, 0.f, 0.f};
    float Up[4] = {0.f, 0.f, 0.f, 0.f};

    // ================= PASS 1: Z and U = sum(e*sim) =================
    for (int st = 0; st < S_SLOTS; st += 64) {
        __syncthreads();
        {   // stage memory tile transposed into mt[d][sl]
            const int sl = tid >> 2, dq = tid & 3;
            const float* mrow = mem + (size_t)(st + sl) * D_DIM;
#pragma unroll
            for (int it = 0; it < 16; ++it) {
                const int d0 = it * 16 + dq * 4;
                const float4 v = *reinterpret_cast<const float4*>(mrow + d0);
                mt[(d0 + 0) * 64 + sl] = v.x;
                mt[(d0 + 1) * 64 + sl] = v.y;
                mt[(d0 + 2) * 64 + sl] = v.z;
                mt[(d0 + 3) * 64 + sl] = v.w;
            }
        }
        if (tid < 64) invl[tid] = invn_g[st + tid];
        __syncthreads();

        float c[4][4];
#pragma unroll
        for (int i = 0; i < 4; ++i)
#pragma unroll
            for (int j = 0; j < 4; ++j) c[i][j] = 0.f;

#pragma unroll 8
        for (int d = 0; d < 256; ++d) {
            const float4 qv = *reinterpret_cast<const float4*>(qT + d * 64 + q0);
            const float4 mv = *reinterpret_cast<const float4*>(mt + d * 64 + s0l);
            c[0][0] += qv.x * mv.x; c[0][1] += qv.x * mv.y; c[0][2] += qv.x * mv.z; c[0][3] += qv.x * mv.w;
            c[1][0] += qv.y * mv.x; c[1][1] += qv.y * mv.y; c[1][2] += qv.y * mv.z; c[1][3] += qv.y * mv.w;
            c[2][0] += qv.z * mv.x; c[2][1] += qv.z * mv.y; c[2][2] += qv.z * mv.z; c[2][3] += qv.z * mv.w;
            c[3][0] += qv.w * mv.x; c[3][1] += qv.w * mv.y; c[3][2] += qv.w * mv.z; c[3][3] += qv.w * mv.w;
        }
        const float iv0 = invl[s0l + 0], iv1 = invl[s0l + 1], iv2 = invl[s0l + 2], iv3 = invl[s0l + 3];
#pragma unroll
        for (int i = 0; i < 4; ++i) {
            float sv[4];
            sv[0] = c[i][0] * iv0; sv[1] = c[i][1] * iv1; sv[2] = c[i][2] * iv2; sv[3] = c[i][3] * iv3;
#pragma unroll
            for (int j = 0; j < 4; ++j) {
                const float e = __expf(sv[j]);
                Zp[i] += e;
                Up[i] += e * sv[j];
            }
        }
    }

    // reduce Z,U over the 16 sg-lanes sharing each q row (within-wave)
#pragma unroll
    for (int off = 8; off > 0; off >>= 1) {
#pragma unroll
        for (int i = 0; i < 4; ++i) {
            Zp[i] += __shfl_xor(Zp[i], off);
            Up[i] += __shfl_xor(Up[i], off);
        }
    }
    float rZ[4];
#pragma unroll
    for (int i = 0; i < 4; ++i) rZ[i] = 1.0f / Zp[i];

    if (sg == 0) {
        float ent = 0.f;
#pragma unroll
        for (int i = 0; i < 4; ++i) ent += logf(Zp[i]) - Up[i] * rZ[i];
        entred[qg] = ent;
    }
    __syncthreads();
    if (tid == 0) {
        float ent = 0.f;
#pragma unroll
        for (int k = 0; k < 16; ++k) ent += entred[k];
        atomicAdd(out + OUT_ENT_IDX, ent * (1.0f / (float)N_TOTAL));
    }

    // ================= PASS 2: weights, retrieval, weights_image =========
    const int dc = tid & 7, qp = tid >> 3;
    const int d0r = dc * 32, q0r = qp * 2;
    float racc[2][32];
#pragma unroll
    for (int k = 0; k < 32; ++k) { racc[0][k] = 0.f; racc[1][k] = 0.f; }

    float* wimg = out + OUT_WIMG_IDX + (size_t)b * S_SLOTS;

    for (int st = 0; st < S_SLOTS; st += 64) {
        __syncthreads();
        {   // stage memory tile (same as pass 1)
            const int sl = tid >> 2, dq = tid & 3;
            const float* mrow = mem + (size_t)(st + sl) * D_DIM;
#pragma unroll
            for (int it = 0; it < 16; ++it) {
                const int d0 = it * 16 + dq * 4;
                const float4 v = *reinterpret_cast<const float4*>(mrow + d0);
                mt[(d0 + 0) * 64 + sl] = v.x;
                mt[(d0 + 1) * 64 + sl] = v.y;
                mt[(d0 + 2) * 64 + sl] = v.z;
                mt[(d0 + 3) * 64 + sl] = v.w;
            }
        }
        if (tid < 64) invl[tid] = invn_g[st + tid];
        __syncthreads();

        float c[4][4];
#pragma unroll
        for (int i = 0; i < 4; ++i)
#pragma unroll
            for (int j = 0; j < 4; ++j) c[i][j] = 0.f;

#pragma unroll 8
        for (int d = 0; d < 256; ++d) {
            const float4 qv = *reinterpret_cast<const float4*>(qT + d * 64 + q0);
            const float4 mv = *reinterpret_cast<const float4*>(mt + d * 64 + s0l);
            c[0][0] += qv.x * mv.x; c[0][1] += qv.x * mv.y; c[0][2] += qv.x * mv.z; c[0][3] += qv.x * mv.w;
            c[1][0] += qv.y * mv.x; c[1][1] += qv.y * mv.y; c[1][2] += qv.y * mv.z; c[1][3] += qv.y * mv.w;
            c[2][0] += qv.z * mv.x; c[2][1] += qv.z * mv.y; c[2][2] += qv.z * mv.z; c[2][3] += qv.z * mv.w;
            c[3][0] += qv.w * mv.x; c[3][1] += qv.w * mv.y; c[3][2] += qv.w * mv.z; c[3][3] += qv.w * mv.w;
        }
        const float iv0 = invl[s0l + 0], iv1 = invl[s0l + 1], iv2 = invl[s0l + 2], iv3 = invl[s0l + 3];
#pragma unroll
        for (int i = 0; i < 4; ++i) {
            float sv[4];
            sv[0] = c[i][0] * iv0; sv[1] = c[i][1] * iv1; sv[2] = c[i][2] * iv2; sv[3] = c[i][3] * iv3;
#pragma unroll
            for (int j = 0; j < 4; ++j) {
                ew[(q0 + i) * 64 + (s0l + j)] = __expf(sv[j]) * rZ[i];
            }
        }
        __syncthreads();

        // weights_image partial: each wave sums 16 q-rows for its column
        {
            const int sl = tid & 63, w = tid >> 6;
            float p = 0.f;
#pragma unroll
            for (int k = 0; k < 16; ++k) p += ew[(w * 16 + k) * 64 + sl];
            atomicAdd(wimg + st + sl, p * (1.0f / 1024.0f));
        }

        // retrieval: racc[qi][k] += sum_s ew[q][s] * mt[d][s]
#pragma unroll 2
        for (int s = 0; s < 64; s += 4) {
            const float4 w0 = *reinterpret_cast<const float4*>(ew + q0r * 64 + s);
            const float4 w1 = *reinterpret_cast<const float4*>(ew + (q0r + 1) * 64 + s);
#pragma unroll
            for (int k = 0; k < 32; ++k) {
                const float4 mv = *reinterpret_cast<const float4*>(mt + (d0r + k) * 64 + s);
                racc[0][k] += w0.x * mv.x + w0.y * mv.y + w0.z * mv.z + w0.w * mv.w;
                racc[1][k] += w1.x * mv.x + w1.y * mv.y + w1.z * mv.z + w1.w * mv.w;
            }
        }
    }

    // ---- soft shrinkage + store retrieved as (B, D, H, W) ----
    float* obase = out + ((size_t)b * D_DIM + d0r) * HW + p0 + q0r;
#pragma unroll
    for (int k = 0; k < 32; ++k) {
        float2 o;
        {
            const float r = racc[0][k];
            const float a = fabsf(r);
            const float lam = fminf(0.005f / (a + 1e-8f), 1.0f);
            o.x = copysignf(a * (1.0f - lam), r);
        }
        {
            const float r = racc[1][k];
            const float a = fabsf(r);
            const float lam = fminf(0.005f / (a + 1e-8f), 1.0f);
            o.y = copysignf(a * (1.0f - lam), r);
        }
        *reinterpret_cast<float2*>(obase + (size_t)k * HW) = o;
    }
}

extern "C" void kernel_launch(void* const* d_in, const int* in_sizes, int n_in,
                              void* d_out, int out_size, void* d_ws, size_t ws_size,
                              hipStream_t stream) {
    const float* feat = (const float*)d_in[0];   // (32,256,32,32) f32
    const float* mem  = (const float*)d_in[1];   // (2048,256) f32
    float* out = (float*)d_out;
    float* invn = (float*)d_ws;                  // 2048 floats scratch

    // zero entropy + weights_image region (retrieved is fully overwritten)
    hipMemsetAsync((char*)d_out + (size_t)OUT_ENT_IDX * 4, 0,
                   (size_t)(1 + 32 * S_SLOTS) * 4, stream);

    k_invnorm<<<S_SLOTS, 64, 0, stream>>>(mem, invn);

    const int lds_bytes = (256 * 64 + 256 * 64 + 64 * 64 + 64 + 64 + 256 + 16) * 4;
    hipFuncSetAttribute((const void*)k_main,
                        hipFuncAttributeMaxDynamicSharedMemorySize, lds_bytes);
    k_main<<<N_TOTAL / 64, 256, lds_bytes, stream>>>(feat, mem, invn, out);
}

// Round 3
// 240.789 us; speedup vs baseline: 14.5154x; 14.5154x over previous
//
#include <hip/hip_runtime.h>
#include <cstdint>
#include <cstddef>

// B=32, D=256, H=W=32 (HW=1024), S=2048, N=32768
#define D_DIM 256
#define S_SLOTS 2048
#define HW_PIX 1024
#define OUT_ENT_IDX 8388608
#define OUT_WIMG_IDX 8388609

using short8 = __attribute__((ext_vector_type(8))) short;
using f32x4  = __attribute__((ext_vector_type(4))) float;

__device__ __forceinline__ unsigned short f2bf(float x) {
    union { float f; unsigned u; } v; v.f = x;
    unsigned r = v.u + 0x7FFF + ((v.u >> 16) & 1);   // RNE
    return (unsigned short)(r >> 16);
}
__device__ __forceinline__ unsigned pack2(float lo, float hi) {
    return (unsigned)f2bf(lo) | ((unsigned)f2bf(hi) << 16);
}
__device__ __forceinline__ void gload16(const void* g, void* l) {
    __builtin_amdgcn_global_load_lds(
        (const __attribute__((address_space(1))) unsigned int*)g,
        (__attribute__((address_space(3))) unsigned int*)l, 16, 0, 0);
}

// ---------------- prep: norms + bf16 swizzled copies into ws ----------------
// mhatg: [s][d] bf16, scaled by 20/||m_s||, 16B-chunk swizzle ^(s&7)  (1 MB)
// mblkg: [tile s/64][d 256][sloc 64] bf16 raw, chunk swizzle ^(d&7)   (1 MB)
__global__ __launch_bounds__(64) void k_prep(const float* __restrict__ mem,
                                             unsigned short* __restrict__ mhatg,
                                             unsigned short* __restrict__ mblkg) {
    const int s = blockIdx.x;
    const int l = threadIdx.x;
    const float4 v = reinterpret_cast<const float4*>(mem + (size_t)s * D_DIM)[l];
    float ss = v.x*v.x + v.y*v.y + v.z*v.z + v.w*v.w;
#pragma unroll
    for (int o = 32; o > 0; o >>= 1) ss += __shfl_xor(ss, o);
    const float sc = 20.0f / fmaxf(sqrtf(ss), 1e-12f);
    {   // mhat
        ushort4 o;
        o.x = f2bf(v.x*sc); o.y = f2bf(v.y*sc); o.z = f2bf(v.z*sc); o.w = f2bf(v.w*sc);
        const int chunk = (l >> 1) ^ (s & 7);
        char* dst = (char*)mhatg + (size_t)s * 512 + (chunk << 4) + 8 * (l & 1);
        *reinterpret_cast<ushort4*>(dst) = o;
    }
    {   // mblkT
        const int tile = s >> 6, sloc = s & 63;
        char* base = (char*)mblkg + (size_t)tile * 32768;
        const float vv[4] = {v.x, v.y, v.z, v.w};
#pragma unroll
        for (int i = 0; i < 4; ++i) {
            const int d = 4*l + i;
            const int byteoff = d * 128 + ((sloc * 2) ^ ((d & 7) << 4));
            *reinterpret_cast<unsigned short*>(base + byteoff) = f2bf(vv[i]);
        }
    }
}

// ---------------- main fused kernel ----------------
// grid 256, block 512 (8 waves). Wave w: wq=w&3 owns q 32wq..+31, ws=w>>2 owns
// s-half of each 64-slot tile. Dynamic LDS: [0,33792) mhat tile / pw / epilogue
// scratch (aliased), [33792, 66560) mblkT tile.
__device__ __forceinline__ void qkt(const char* mh, const short8 (&qfrag)[2][8],
                                    int srow, int g, int l15, f32x4 (&acc)[2][2]) {
#pragma unroll
    for (int kk = 0; kk < 8; ++kk) {
        const int c0 = ((4*kk + g) ^ (l15 & 7)) << 4;
        const short8 a0 = *reinterpret_cast<const short8*>(mh + srow*512 + c0);
        const short8 a1 = *reinterpret_cast<const short8*>(mh + (srow+16)*512 + c0);
        acc[0][0] = __builtin_amdgcn_mfma_f32_16x16x32_bf16(a0, qfrag[0][kk], acc[0][0], 0,0,0);
        acc[0][1] = __builtin_amdgcn_mfma_f32_16x16x32_bf16(a0, qfrag[1][kk], acc[0][1], 0,0,0);
        acc[1][0] = __builtin_amdgcn_mfma_f32_16x16x32_bf16(a1, qfrag[0][kk], acc[1][0], 0,0,0);
        acc[1][1] = __builtin_amdgcn_mfma_f32_16x16x32_bf16(a1, qfrag[1][kk], acc[1][1], 0,0,0);
    }
}

__global__ __launch_bounds__(512, 2) void k_main(
    const float* __restrict__ feat, const char* __restrict__ mhat_g,
    const char* __restrict__ mblk_g, float* __restrict__ out)
{
    extern __shared__ char dyn[];
    __shared__ float sm_norm[512];
    __shared__ float qs_lds[128];
    __shared__ float zb[2][4][2][16];
    __shared__ float ub[2][4][2][16];
    __shared__ float rZbuf[128];
    __shared__ float entb[4];

    const int tid  = threadIdx.x;
    const int lane = tid & 63;
    const int w    = tid >> 6;
    const int wq   = w & 3;
    const int ws   = w >> 2;
    const int l15  = lane & 15;
    const int g    = (lane >> 4) & 3;
    const int blk  = blockIdx.x;
    const int b    = blk >> 3;
    const int p0   = (blk & 7) * 128;
    const float* fbase = feat + (size_t)b * (D_DIM * HW_PIX);
    float* wimg_g = out + OUT_WIMG_IDX;

    // ---- query norms ----
    {
        const int dp = tid >> 7, pp = tid & 127;
        const float* fp = fbase + (size_t)(dp*64)*HW_PIX + p0 + pp;
        float ss = 0.f;
#pragma unroll 8
        for (int d = 0; d < 64; ++d) { const float v = fp[(size_t)d*HW_PIX]; ss += v*v; }
        sm_norm[dp*128 + pp] = ss;
    }
    __syncthreads();
    if (tid < 128) {
        const float n2 = sm_norm[tid] + sm_norm[128+tid] + sm_norm[256+tid] + sm_norm[384+tid];
        qs_lds[tid] = 1.0f / fmaxf(sqrtf(n2), 1e-12f);
    }
    __syncthreads();

    // ---- build Q B-fragments (bf16, q-hat) in registers ----
    short8 qfrag[2][8];
#pragma unroll
    for (int tq = 0; tq < 2; ++tq) {
        const int q = 32*wq + 16*tq + l15;
        const float qs = qs_lds[q];
        const float* fq = fbase + p0 + q;
#pragma unroll
        for (int kk = 0; kk < 8; ++kk) {
            union { short8 s; unsigned u[4]; } fr;
#pragma unroll
            for (int jp = 0; jp < 4; ++jp) {
                const int d = 32*kk + 8*g + 2*jp;
                fr.u[jp] = pack2(fq[(size_t)d*HW_PIX] * qs, fq[(size_t)(d+1)*HW_PIX] * qs);
            }
            qfrag[tq][kk] = fr.s;
        }
    }

    const int srow = 32*ws + l15;

    // ================= PASS A: Z, U =================
    float Zp[2] = {0.f, 0.f}, Up[2] = {0.f, 0.f};
    for (int st = 0; st < 32; ++st) {
        const char* gsrc = mhat_g + (size_t)st * 32768;
#pragma unroll
        for (int i = 0; i < 4; ++i)
            gload16(gsrc + tid*16 + i*8192, dyn + tid*16 + i*8192);
        __syncthreads();
        f32x4 acc[2][2] = {};
        qkt(dyn, qfrag, srow, g, l15, acc);
#pragma unroll
        for (int ts = 0; ts < 2; ++ts)
#pragma unroll
            for (int tq = 0; tq < 2; ++tq)
#pragma unroll
                for (int r = 0; r < 4; ++r) {
                    const float sim = acc[ts][tq][r];
                    const float e = __expf(sim);
                    Zp[tq] += e; Up[tq] += e * sim;
                }
        __syncthreads();
    }
#pragma unroll
    for (int tq = 0; tq < 2; ++tq) {
        Zp[tq] += __shfl_xor(Zp[tq], 16); Zp[tq] += __shfl_xor(Zp[tq], 32);
        Up[tq] += __shfl_xor(Up[tq], 16); Up[tq] += __shfl_xor(Up[tq], 32);
    }
    if (lane < 16) {
#pragma unroll
        for (int tq = 0; tq < 2; ++tq) {
            zb[ws][wq][tq][lane] = Zp[tq];
            ub[ws][wq][tq][lane] = Up[tq];
        }
    }
    __syncthreads();
    float rZ[2], rZw[2];
    {
        float Zf[2], Uf[2];
#pragma unroll
        for (int tq = 0; tq < 2; ++tq) {
            Zf[tq] = Zp[tq] + zb[1-ws][wq][tq][l15];
            Uf[tq] = Up[tq] + ub[1-ws][wq][tq][l15];
            rZ[tq] = 1.0f / Zf[tq];
            rZw[tq] = rZ[tq] * (1.0f/1024.0f);
        }
        if (ws == 0 && lane < 16) {
            rZbuf[32*wq + l15]      = rZ[0];
            rZbuf[32*wq + 16 + l15] = rZ[1];
            float ent = 0.f;
#pragma unroll
            for (int tq = 0; tq < 2; ++tq) ent += __logf(Zf[tq]) - Uf[tq] * rZ[tq];
            ent += __shfl_xor(ent, 1); ent += __shfl_xor(ent, 2);
            ent += __shfl_xor(ent, 4); ent += __shfl_xor(ent, 8);
            if (lane == 0) entb[wq] = ent;
        }
    }
    __syncthreads();
    if (tid == 0)
        atomicAdd(out + OUT_ENT_IDX, (entb[0]+entb[1]+entb[2]+entb[3]) * (1.0f/32768.0f));

    // ================= PASS B: PV + wimg =================
    f32x4 acc_o[2][16] = {};
    for (int st = 0; st < 32; ++st) {
        const char* gsrcA = mhat_g + (size_t)st * 32768;
        const char* gsrcB = mblk_g + (size_t)st * 32768;
#pragma unroll
        for (int i = 0; i < 4; ++i) {
            gload16(gsrcA + tid*16 + i*8192, dyn + tid*16 + i*8192);
            gload16(gsrcB + tid*16 + i*8192, dyn + 33792 + tid*16 + i*8192);
        }
        __syncthreads();
        f32x4 acc[2][2] = {};
        qkt(dyn, qfrag, srow, g, l15, acc);
        float ev[2][2][4];
#pragma unroll
        for (int ts = 0; ts < 2; ++ts)
#pragma unroll
            for (int tq = 0; tq < 2; ++tq)
#pragma unroll
                for (int r = 0; r < 4; ++r)
                    ev[ts][tq][r] = __expf(acc[ts][tq][r]);
        __syncthreads();   // QK^T reads done; pw aliases mhat region
        // pw[64][132] f32: weights (e*rZ/1024) for this tile
#pragma unroll
        for (int ts = 0; ts < 2; ++ts)
#pragma unroll
            for (int tq = 0; tq < 2; ++tq) {
                const int q = 32*wq + 16*tq + l15;
#pragma unroll
                for (int r = 0; r < 4; ++r) {
                    const int s = 32*ws + 16*ts + 4*g + r;
                    *reinterpret_cast<float*>(dyn + s*528 + q*4) = ev[ts][tq][r] * rZw[tq];
                }
            }
        __syncthreads();
        {   // wimg reduce over q
            const int s_r = tid >> 3, qc = tid & 7;
            const char* pr = dyn + s_r*528 + qc*64;
            float ps = 0.f;
#pragma unroll
            for (int i = 0; i < 4; ++i) {
                const f32x4 v = *reinterpret_cast<const f32x4*>(pr + i*16);
                ps += v[0] + v[1] + v[2] + v[3];
            }
            ps += __shfl_xor(ps, 1); ps += __shfl_xor(ps, 2); ps += __shfl_xor(ps, 4);
            if (qc == 0) atomicAdd(wimg_g + (size_t)b*2048 + st*64 + s_r, ps);
        }
        // repack P (C-layout f32) -> A-fragments (bf16), in registers
        short8 pfrag[2];
#pragma unroll
        for (int tq = 0; tq < 2; ++tq) {
            const unsigned u00 = pack2(ev[0][tq][0], ev[0][tq][1]);
            const unsigned u01 = pack2(ev[0][tq][2], ev[0][tq][3]);
            const unsigned u10 = pack2(ev[1][tq][0], ev[1][tq][1]);
            const unsigned u11 = pack2(ev[1][tq][2], ev[1][tq][3]);
            const int sA = l15 + 32*(g & 1);
            const int sB = sA + 16;
            const unsigned a00 = __shfl((int)u00, sA), a10 = __shfl((int)u10, sA);
            const unsigned a01 = __shfl((int)u01, sA), a11 = __shfl((int)u11, sA);
            const unsigned b00 = __shfl((int)u00, sB), b10 = __shfl((int)u10, sB);
            const unsigned b01 = __shfl((int)u01, sB), b11 = __shfl((int)u11, sB);
            const bool hi = (lane & 32) != 0;
            union { short8 s; unsigned u[4]; } fr;
            fr.u[0] = hi ? a10 : a00;
            fr.u[1] = hi ? a11 : a01;
            fr.u[2] = hi ? b10 : b00;
            fr.u[3] = hi ? b11 : b01;
            pfrag[tq] = fr.s;
        }
        // PV: O[q][d] += P[q][s] * M[s][d]  (K=32 = wave's s-half)
#pragma unroll
        for (int Dt = 0; Dt < 16; ++Dt) {
            const int d = 16*Dt + l15;
            const int byteoff = 33792 + d*128 + (((4*ws + g) ^ (l15 & 7)) << 4);
            const short8 bf = *reinterpret_cast<const short8*>(dyn + byteoff);
            acc_o[0][Dt] = __builtin_amdgcn_mfma_f32_16x16x32_bf16(pfrag[0], bf, acc_o[0][Dt], 0,0,0);
            acc_o[1][Dt] = __builtin_amdgcn_mfma_f32_16x16x32_bf16(pfrag[1], bf, acc_o[1][Dt], 0,0,0);
        }
        __syncthreads();
    }

    // ================= epilogue: combine ws halves, normalize, shrink, store ====
    float rZq[2][4];
#pragma unroll
    for (int tq = 0; tq < 2; ++tq)
#pragma unroll
        for (int r = 0; r < 4; ++r)
            rZq[tq][r] = rZbuf[32*wq + 16*tq + 4*g + r];

#pragma unroll
    for (int Dt = 0; Dt < 16; ++Dt) {
        if (ws == 1) {
#pragma unroll
            for (int tq = 0; tq < 2; ++tq)
                *reinterpret_cast<f32x4*>(dyn + ((wq*2 + tq)*64 + lane)*16) = acc_o[tq][Dt];
        }
        __syncthreads();
        if (ws == 0) {
#pragma unroll
            for (int tq = 0; tq < 2; ++tq) {
                const f32x4 other = *reinterpret_cast<const f32x4*>(dyn + ((wq*2 + tq)*64 + lane)*16);
#pragma unroll
                for (int r = 0; r < 4; ++r) {
                    const float o = (acc_o[tq][Dt][r] + other[r]) * rZq[tq][r];
                    const float a = fabsf(o);
                    const float lam = fminf(0.005f / (a + 1e-8f), 1.0f);
                    const float val = copysignf(a * (1.0f - lam), o);
                    const int q = 32*wq + 16*tq + 4*g + r;
                    *reinterpret_cast<float*>(dyn + 8192 + q*84 + l15*4) = val;
                }
            }
        }
        __syncthreads();
#pragma unroll
        for (int i = 0; i < 4; ++i) {
            const int flat = i*512 + tid;
            const int dd = flat >> 7, q = flat & 127;
            const float val = *reinterpret_cast<const float*>(dyn + 8192 + q*84 + dd*4);
            out[((size_t)b*256 + Dt*16 + dd)*HW_PIX + p0 + q] = val;
        }
        __syncthreads();
    }
}

extern "C" void kernel_launch(void* const* d_in, const int* in_sizes, int n_in,
                              void* d_out, int out_size, void* d_ws, size_t ws_size,
                              hipStream_t stream) {
    const float* feat = (const float*)d_in[0];   // (32,256,32,32) f32
    const float* mem  = (const float*)d_in[1];   // (2048,256) f32
    float* out = (float*)d_out;

    unsigned short* mhat_g = (unsigned short*)d_ws;                       // 1 MB
    unsigned short* mblk_g = (unsigned short*)((char*)d_ws + (1 << 20));  // 1 MB

    // zero entropy + weights_image (retrieved fully overwritten)
    hipMemsetAsync((char*)d_out + (size_t)OUT_ENT_IDX * 4, 0,
                   (size_t)(1 + 32 * S_SLOTS) * 4, stream);

    k_prep<<<S_SLOTS, 64, 0, stream>>>(mem, mhat_g, mblk_g);

    const int lds_bytes = 66560;
    hipFuncSetAttribute((const void*)k_main,
                        hipFuncAttributeMaxDynamicSharedMemorySize, lds_bytes);
    k_main<<<256, 512, lds_bytes, stream>>>(feat, (const char*)mhat_g,
                                            (const char*)mblk_g, out);
}